// Round 1
// baseline (1036.235 us; speedup 1.0000x reference)
//
#include <hip/hip_runtime.h>
#include <stdint.h>

typedef unsigned short u16;
typedef __bf16 bf16x8 __attribute__((ext_vector_type(8)));
typedef float f32x4 __attribute__((ext_vector_type(4)));

#define S_DIM 4096
#define D_DIM 512
#define B_DIM 4
#define L_DIM 8921
#define LPAD  8960   // L padded to multiple of 128
#define M1    16384  // B*S

__device__ __forceinline__ u16 f2bf(float f) {
  uint32_t u = __float_as_uint(f);
  u += 0x7FFFu + ((u >> 16) & 1u);   // RNE
  return (u16)(u >> 16);
}
__device__ __forceinline__ float bf2f(u16 u) {
  return __uint_as_float(((uint32_t)u) << 16);
}
__device__ __forceinline__ void async16(const u16* g, u16* l) {
  __builtin_amdgcn_global_load_lds((const __attribute__((address_space(1))) void*)g,
                                   (__attribute__((address_space(3))) void*)l, 16, 0, 0);
}

// ---------------- cast f32 -> bf16 with optional zero tail padding ----------
__global__ __launch_bounds__(256) void cast_pad_kernel(const float* __restrict__ src,
                                                       u16* __restrict__ dst,
                                                       long long nsrc, long long ndst) {
  long long i = ((long long)blockIdx.x * 256 + threadIdx.x) * 4;
  if (i >= ndst) return;
  ushort4 o;
  if (i < nsrc) {
    float4 v = *(const float4*)(src + i);
    o.x = f2bf(v.x); o.y = f2bf(v.y); o.z = f2bf(v.z); o.w = f2bf(v.w);
  } else {
    o.x = 0; o.y = 0; o.z = 0; o.w = 0;
  }
  *(ushort4*)(dst + i) = o;
}

// ---------------- shared 128x128xK NT GEMM core (m97 structure) -------------
// C[tileM+128][tileN+128] += A[M,K] * B[N,K]^T, K=512, bf16, f32 acc.
__device__ __forceinline__ void gemm_core(const u16* __restrict__ A, const u16* __restrict__ B,
                                          int tileM, int tileN, u16* Al, u16* Bl,
                                          f32x4 acc[4][4], int waveM, int waveN,
                                          int quad, int l16) {
  const int t = threadIdx.x;
  const int r0 = t >> 2, c0 = (t & 3) * 8;
  for (int k0 = 0; k0 < D_DIM; k0 += 32) {
    // stage 128x32 bf16 tiles of A and B: 512 16B chunks each, 2 per thread
    async16(A + (size_t)(tileM + r0) * D_DIM + k0 + c0,        Al + t * 8);
    async16(A + (size_t)(tileM + r0 + 64) * D_DIM + k0 + c0,   Al + (t + 256) * 8);
    async16(B + (size_t)(tileN + r0) * D_DIM + k0 + c0,        Bl + t * 8);
    async16(B + (size_t)(tileN + r0 + 64) * D_DIM + k0 + c0,   Bl + (t + 256) * 8);
    __syncthreads();   // drains vmcnt for global_load_lds
    bf16x8 af[4], bfr[4];
#pragma unroll
    for (int mi = 0; mi < 4; ++mi)
      af[mi] = *(const bf16x8*)&Al[(waveM + mi * 16 + l16) * 32 + quad * 8];
#pragma unroll
    for (int ni = 0; ni < 4; ++ni)
      bfr[ni] = *(const bf16x8*)&Bl[(waveN + ni * 16 + l16) * 32 + quad * 8];
#pragma unroll
    for (int mi = 0; mi < 4; ++mi)
#pragma unroll
      for (int ni = 0; ni < 4; ++ni)
        acc[mi][ni] = __builtin_amdgcn_mfma_f32_16x16x32_bf16(af[mi], bfr[ni], acc[mi][ni], 0, 0, 0);
    __syncthreads();   // before next-iter LDS overwrite
  }
}

// ---------------- GEMM1: weights = tanh(x @ W1^T), bf16 out -----------------
__global__ __launch_bounds__(256) void gemm1_tanh(const u16* __restrict__ A,  // x_bf [16384,512]
                                                  const u16* __restrict__ B,  // W1_bf [512,512]
                                                  u16* __restrict__ C) {      // weights [16384,512]
  __shared__ __align__(16) u16 Al[128 * 32];
  __shared__ __align__(16) u16 Bl[128 * 32];
  const int t = threadIdx.x, lane = t & 63, wave = t >> 6;
  const int quad = lane >> 4, l16 = lane & 15;
  const int tileM = blockIdx.y * 128, tileN = blockIdx.x * 128;
  const int waveM = (wave >> 1) * 64, waveN = (wave & 1) * 64;
  f32x4 acc[4][4];
  const f32x4 z = {0.f, 0.f, 0.f, 0.f};
#pragma unroll
  for (int mi = 0; mi < 4; ++mi)
#pragma unroll
    for (int ni = 0; ni < 4; ++ni) acc[mi][ni] = z;
  gemm_core(A, B, tileM, tileN, Al, Bl, acc, waveM, waveN, quad, l16);
#pragma unroll
  for (int mi = 0; mi < 4; ++mi) {
    const int m0 = tileM + waveM + mi * 16 + quad * 4;
#pragma unroll
    for (int ni = 0; ni < 4; ++ni) {
      const int n = tileN + waveN + ni * 16 + l16;
#pragma unroll
      for (int r = 0; r < 4; ++r)
        C[(size_t)(m0 + r) * D_DIM + n] = f2bf(tanhf(acc[mi][ni][r]));
    }
  }
}

// ---------------- GEMM2: exp(W2 @ weights_b^T) + rowsum ---------------------
// BF16WS=true: store bf16 exp-scores into workspace; else f32 into d_out att.
template <bool BF16WS>
__global__ __launch_bounds__(256) void gemm2_exp(const u16* __restrict__ A,    // W2_bf [8960,512]
                                                 const u16* __restrict__ Ball, // weights [16384,512]
                                                 u16* __restrict__ scores,     // [4,8921,4096] bf16
                                                 float* __restrict__ attout,   // [4,8921,4096] f32
                                                 float* __restrict__ rowsum) { // [4,8960]
  __shared__ __align__(16) u16 Al[128 * 32];
  __shared__ __align__(16) u16 Bl[128 * 32];
  const int b = blockIdx.z;
  const u16* B = Ball + (size_t)b * S_DIM * D_DIM;
  const int t = threadIdx.x, lane = t & 63, wave = t >> 6;
  const int quad = lane >> 4, l16 = lane & 15;
  const int tileM = blockIdx.y * 128, tileN = blockIdx.x * 128;
  const int waveM = (wave >> 1) * 64, waveN = (wave & 1) * 64;
  f32x4 acc[4][4];
  const f32x4 z = {0.f, 0.f, 0.f, 0.f};
#pragma unroll
  for (int mi = 0; mi < 4; ++mi)
#pragma unroll
    for (int ni = 0; ni < 4; ++ni) acc[mi][ni] = z;
  gemm_core(A, B, tileM, tileN, Al, Bl, acc, waveM, waveN, quad, l16);

#pragma unroll
  for (int mi = 0; mi < 4; ++mi) {
    const int l0 = tileM + waveM + mi * 16 + quad * 4;
    float rs[4] = {0.f, 0.f, 0.f, 0.f};
#pragma unroll
    for (int ni = 0; ni < 4; ++ni) {
      const int s = tileN + waveN + ni * 16 + l16;
#pragma unroll
      for (int r = 0; r < 4; ++r) {
        const float ev = __expf(acc[mi][ni][r]);
        rs[r] += ev;
        const int l = l0 + r;
        if (l < L_DIM) {
          const size_t off = ((size_t)b * L_DIM + l) * S_DIM + s;
          if (BF16WS) scores[off] = f2bf(ev);
          else        attout[off] = ev;
        }
      }
    }
#pragma unroll
    for (int r = 0; r < 4; ++r) {   // reduce over the 16 columns held by this quad-group
      float v = rs[r];
      v += __shfl_xor(v, 1);
      v += __shfl_xor(v, 2);
      v += __shfl_xor(v, 4);
      v += __shfl_xor(v, 8);
      if (l16 == 0) atomicAdd(&rowsum[(size_t)b * LPAD + l0 + r], v);
    }
  }
}

// ---------------- normalize + colsum ---------------------------------------
template <bool BF16WS>
__global__ __launch_bounds__(256) void normalize_colsum(const u16* __restrict__ scores,
                                                        const float* __restrict__ rowsum,
                                                        float* __restrict__ att,
                                                        float* __restrict__ colsum) {
  const int b = blockIdx.y;
  const int l0 = blockIdx.x * 32;
  const int t = threadIdx.x;
  __shared__ float sc[32];
  if (t < 32) {
    const int l = l0 + t;
    sc[t] = (l < L_DIM) ? 1.0f / rowsum[(size_t)b * LPAD + l] : 0.0f;
  }
  __syncthreads();
#pragma unroll
  for (int p = 0; p < 4; ++p) {
    const int s = p * 1024 + t * 4;
    float c0 = 0.f, c1 = 0.f, c2 = 0.f, c3 = 0.f;
    for (int i = 0; i < 32; ++i) {
      const int l = l0 + i;
      if (l >= L_DIM) break;
      const size_t off = ((size_t)b * L_DIM + l) * S_DIM + s;
      const float scale = sc[i];
      float v0, v1, v2, v3;
      if (BF16WS) {
        ushort4 u = *(const ushort4*)(scores + off);
        v0 = bf2f(u.x) * scale; v1 = bf2f(u.y) * scale;
        v2 = bf2f(u.z) * scale; v3 = bf2f(u.w) * scale;
      } else {
        float4 u = *(const float4*)(att + off);
        v0 = u.x * scale; v1 = u.y * scale; v2 = u.z * scale; v3 = u.w * scale;
      }
      float4 o = {v0, v1, v2, v3};
      *(float4*)(att + off) = o;
      c0 += v0; c1 += v1; c2 += v2; c3 += v3;
    }
    float* cs = colsum + (size_t)b * S_DIM + s;
    atomicAdd(cs + 0, c0); atomicAdd(cs + 1, c1);
    atomicAdd(cs + 2, c2); atomicAdd(cs + 3, c3);
  }
}

// ---------------- out[b,d] = sum_s colsum[b,s]*x[b,s,d] / R -----------------
__global__ __launch_bounds__(256) void out_kernel(const float* __restrict__ x,
                                                  const float* __restrict__ colsum,
                                                  float* __restrict__ out) {
  const int b = blockIdx.y, s0 = blockIdx.x * 128, t = threadIdx.x;
  float a0 = 0.f, a1 = 0.f;
  for (int i = 0; i < 128; ++i) {
    const int s = s0 + i;
    const float c = colsum[(size_t)b * S_DIM + s];
    const float* xr = x + ((size_t)b * S_DIM + s) * D_DIM;
    a0 += c * xr[t];
    a1 += c * xr[t + 256];
  }
  const float invR = 1.0f / 8921.0f;
  atomicAdd(out + b * D_DIM + t,       a0 * invR);
  atomicAdd(out + b * D_DIM + t + 256, a1 * invR);
}

extern "C" void kernel_launch(void* const* d_in, const int* in_sizes, int n_in,
                              void* d_out, int out_size, void* d_ws, size_t ws_size,
                              hipStream_t stream) {
  const float* x  = (const float*)d_in[0];   // [4,4096,512]
  const float* W1 = (const float*)d_in[1];   // [512,512]
  const float* W2 = (const float*)d_in[2];   // [8921,512]
  float* out = (float*)d_out;                // 2048 + 4*8921*4096
  float* att = out + 2048;

  char* ws = (char*)d_ws;
  u16*   x_bf   = (u16*)(ws + 0);            // 16,777,216 B
  u16*   wt_bf  = (u16*)(ws + 16777216);     // 16,777,216 B
  u16*   w1_bf  = (u16*)(ws + 33554432);     //    524,288 B
  u16*   w2_bf  = (u16*)(ws + 34078720);     //  9,175,040 B
  float* rowsum = (float*)(ws + 43253760);   //    143,360 B
  float* colsum = (float*)(ws + 43397120);   //     65,536 B
  u16*   scores = (u16*)(ws + 43462656);     // 292,323,328 B (big path only)
  const size_t need_big = 43462656ull + (size_t)B_DIM * L_DIM * S_DIM * 2ull;
  const bool big = ws_size >= need_big;

  hipMemsetAsync(rowsum, 0, (size_t)B_DIM * LPAD * 4, stream);
  hipMemsetAsync(colsum, 0, (size_t)B_DIM * S_DIM * 4, stream);
  hipMemsetAsync(out, 0, 2048 * sizeof(float), stream);

  cast_pad_kernel<<<8192, 256, 0, stream>>>(x,  x_bf,  8388608LL, 8388608LL);
  cast_pad_kernel<<<256,  256, 0, stream>>>(W1, w1_bf, 262144LL,  262144LL);
  cast_pad_kernel<<<4480, 256, 0, stream>>>(W2, w2_bf, (long long)L_DIM * 512, (long long)LPAD * 512);

  gemm1_tanh<<<dim3(4, 128), 256, 0, stream>>>(x_bf, w1_bf, wt_bf);

  dim3 g2(S_DIM / 128, LPAD / 128, B_DIM);   // (32, 70, 4)
  if (big) {
    gemm2_exp<true><<<g2, 256, 0, stream>>>(w2_bf, wt_bf, scores, att, rowsum);
    normalize_colsum<true><<<dim3(279, 4), 256, 0, stream>>>(scores, rowsum, att, colsum);
  } else {
    gemm2_exp<false><<<g2, 256, 0, stream>>>(w2_bf, wt_bf, scores, att, rowsum);
    normalize_colsum<false><<<dim3(279, 4), 256, 0, stream>>>(scores, rowsum, att, colsum);
  }

  out_kernel<<<dim3(32, 4), 256, 0, stream>>>(x, colsum, out);
}